// Round 9
// baseline (1282.055 us; speedup 1.0000x reference)
//
#include <hip/hip_runtime.h>
#include <hip/hip_bf16.h>

// ---------------------------------------------------------------------------
// VAE + supervised MoE forward, MI355X.
//   k_prep_enc: one-time 3-way bf16 split of encoder conv2/conv3 weights
//   k_conv12 : conv1 fp32 exact + conv2 via 3-split bf16 MFMA -> h2f fp32
//   k_conv3  : 1-sample blocks (20.5KB LDS -> 4-5 blocks/CU for B-load
//              latency hiding), 3-split MFMA, static unrolls; h3 in-place
//   k_fc     : h3(stride 12544) @ [w_mu|w_lv], K-split 2 (fp32)
//   k_gate   : mu/lv, z, gating MLP, softmax, argmax (strict fp32)
//   k_prep   : decoder weight repack to bf16 (into dead part region)
//   k_dfc    : z @ d_fc_w[e] + b -> hfcb bf16 (float4 weight stream)
//   k_d1     : up2+conv(32->64)+elu via bf16 MFMA -> d1o
//   k_d23    : up2+conv(64->32)+elu fused conv(32->1)+sigmoid, all on MFMA
// Only the argmax expert is decoded per sample. Gating stays fp32-accurate.
// ---------------------------------------------------------------------------

#define NB 2048

typedef short bf16x8 __attribute__((ext_vector_type(8)));
typedef float f32x4  __attribute__((ext_vector_type(4)));

static constexpr int OFF_RECON  = 0;
static constexpr int OFF_MU     = 1605632;
static constexpr int OFF_LV     = 1736704;
static constexpr int OFF_LOGITS = 1867776;
static constexpr int OFF_PROBS  = 1884160;

// workspace layout (float units)
static constexpr size_t WS_U    = 0;         // 25,690,112 fl
static constexpr size_t WS_PART = 25690112;  // 524,288 fl
static constexpr size_t WS_Z    = 26214400;  // 131,072 fl
static constexpr size_t WS_IDX  = 26345472;  // 2,048 ints = 512 fl
static constexpr size_t WS_WENC = 26345984;  // encoder split weights
static constexpr size_t W2S_OFF = 0;         // 110,592 fl
static constexpr size_t W3S_OFF = 110592;    // 442,368 fl
static constexpr size_t HFC_OFF = 0;         // hfcb bf16 [n][49][32] in U
static constexpr size_t D1O_OFF = 3211264;   // d1o bf16 [n][196][64] in U
static constexpr size_t W1B_OFF = 0;         // in part region
static constexpr size_t WCB_OFF = 73728;     // in part region

__device__ __forceinline__ float relu_f(float v) { return v > 0.f ? v : 0.f; }
__device__ __forceinline__ float elu_f(float v)  { return v > 0.f ? v : expm1f(v); }
__device__ __forceinline__ short f2b(float v) {
  __hip_bfloat16 h = __float2bfloat16(v);
  short s; __builtin_memcpy(&s, &h, 2); return s;
}
__device__ __forceinline__ float s2f(short s) {
  unsigned v = ((unsigned)(unsigned short)s) << 16;
  float f; __builtin_memcpy(&f, &v, 4); return f;
}
__device__ __forceinline__ float blo(unsigned u) {
  unsigned v = u << 16; float f; __builtin_memcpy(&f, &v, 4); return f;
}
__device__ __forceinline__ float bhi(unsigned u) {
  unsigned v = u & 0xffff0000u; float f; __builtin_memcpy(&f, &v, 4); return f;
}

// ---------------------------------------------------------------------------
// one-time encoder weight 3-split (h,m,l), slot-duplicated x4 along k.
// ---------------------------------------------------------------------------
__global__ __launch_bounds__(256) void k_prep_enc(
    const float* __restrict__ ew2, const float* __restrict__ ew3,
    unsigned short* __restrict__ w2s, unsigned short* __restrict__ w3s)
{
  const int u = blockIdx.x * 256 + threadIdx.x;
  if (u >= 276480) return;
  float w; uint2* dst; int pass;
  if (u < 55296) {
    int chunk = u / 13824, r = u % 13824;
    pass = r / 4608; int r2 = r % 4608;
    int tap = r2 / 512, r3 = r2 % 512;
    int oc = r3 / 8, ic = r3 % 8;
    w = ew2[oc * 288 + (chunk * 8 + ic) * 9 + tap];
    dst = (uint2*)w2s + u;
  } else {
    int u2 = u - 55296;
    int chunk = u2 / 27648, r = u2 % 27648;
    pass = r / 9216; int r2 = r % 9216;
    int tap = r2 / 1024, r3 = r2 % 1024;
    int oc = r3 / 8, ic = r3 % 8;
    w = ew3[oc * 576 + (chunk * 8 + ic) * 9 + tap];
    dst = (uint2*)w3s + u2;
  }
  short h = f2b(w); float hf = s2f(h);
  short mm = f2b(w - hf); float mf = s2f(mm);
  short ll = f2b(w - hf - mf);
  short val = (pass == 0) ? h : (pass == 1) ? mm : ll;
  unsigned vv = (unsigned)(unsigned short)val | ((unsigned)(unsigned short)val << 16);
  uint2 pk; pk.x = vv; pk.y = vv;
  *dst = pk;
}

// ---------------------------------------------------------------------------
// conv1 (1->32, exact fp32) fused with conv2 (32->64, s2) via 3-split MFMA.
// ---------------------------------------------------------------------------
__global__ __launch_bounds__(256, 2) void k_conv12(
    const float* __restrict__ x,
    const float* __restrict__ w1, const float* __restrict__ b1,
    const float* __restrict__ b2g, const unsigned short* __restrict__ w2s,
    float* __restrict__ h2f)
{
  __shared__ float sX[900];
  __shared__ float sB2[64];
  __shared__ __align__(16) short sH[900 * 40];

  const int n = blockIdx.x, t = threadIdx.x;

  for (int idx = t; idx < 900; idx += 256) {
    int yy = idx / 30, xx = idx % 30;
    float v = 0.f;
    if (yy >= 1 && yy <= 28 && xx >= 1 && xx <= 28)
      v = x[n * 784 + (yy - 1) * 28 + (xx - 1)];
    sX[idx] = v;
  }
  if (t < 64) sB2[t] = b2g[t];
  for (int bi = t; bi < 116; bi += 256) {
    int p;
    if (bi < 30) p = bi;
    else if (bi < 60) p = 870 + (bi - 30);
    else if (bi < 88) p = (bi - 59) * 30;
    else p = (bi - 87) * 30 + 29;
    unsigned* d = (unsigned*)&sH[p * 40];
    #pragma unroll
    for (int j = 0; j < 20; ++j) d[j] = 0u;
  }
  __syncthreads();

  float xw[4][9];
  int hp[4]; bool pvld[4];
  #pragma unroll
  for (int i = 0; i < 4; ++i) {
    int p = t + 256 * i;
    pvld[i] = (p < 784);
    int yy = pvld[i] ? p / 28 : 0, xx = pvld[i] ? p % 28 : 0;
    hp[i] = (yy + 1) * 30 + xx + 1;
    #pragma unroll
    for (int k = 0; k < 9; ++k)
      xw[i][k] = sX[(yy + k / 3) * 30 + xx + (k % 3)];
  }

  const int lane = t & 63, wv = t >> 6;
  const int q = lane >> 4, m16 = lane & 15;
  const int nth = wv & 1, mh = wv >> 1;

  int abase[7];
  #pragma unroll
  for (int mtl = 0; mtl < 7; ++mtl) {
    int m = (mh * 7 + mtl) * 16 + m16; if (m > 195) m = 195;
    int yy = m / 14, xx = m % 14;
    abase[mtl] = (yy * 60 + xx * 2) * 40 + q * 8;
  }
  f32x4 acc[7][2];
  #pragma unroll
  for (int a = 0; a < 7; ++a) { acc[a][0] = (f32x4)0.f; acc[a][1] = (f32x4)0.f; }

  for (int c = 0; c < 4; ++c) {
    #pragma unroll
    for (int o = 0; o < 8; ++o) {
      const int oc = c * 8 + o;
      float wr[9];
      #pragma unroll
      for (int k = 0; k < 9; ++k) wr[k] = w1[oc * 9 + k];
      const float bb = b1[oc];
      #pragma unroll
      for (int i = 0; i < 4; ++i) if (pvld[i]) {
        float v = bb;
        #pragma unroll
        for (int k = 0; k < 9; ++k) v += xw[i][k] * wr[k];
        v = relu_f(v);
        short h = f2b(v); float hf = s2f(h);
        short mm = f2b(v - hf); float mf = s2f(mm);
        short ll = f2b(v - hf - mf);
        uint2 pk;
        pk.x = (unsigned)(unsigned short)h | ((unsigned)(unsigned short)mm << 16);
        pk.y = (unsigned)(unsigned short)ll;
        *(uint2*)&sH[hp[i] * 40 + o * 4] = pk;
      }
    }
    __syncthreads();

    const unsigned short* wb = w2s + (size_t)c * 55296;
    for (int tap = 0; tap < 9; ++tap) {
      const int toff = ((tap / 3) * 30 + (tap % 3)) * 40;
      bf16x8 A[7];
      #pragma unroll
      for (int mtl = 0; mtl < 7; ++mtl)
        A[mtl] = *(const bf16x8*)&sH[abase[mtl] + toff];
      #pragma unroll
      for (int pass = 0; pass < 3; ++pass) {
        #pragma unroll
        for (int ntl = 0; ntl < 2; ++ntl) {
          const int ocl = nth * 32 + ntl * 16 + m16;
          bf16x8 B = *(const bf16x8*)&wb[((pass * 9 + tap) * 64 + ocl) * 32 + q * 8];
          #pragma unroll
          for (int mtl = 0; mtl < 7; ++mtl)
            acc[mtl][ntl] = __builtin_amdgcn_mfma_f32_16x16x32_bf16(A[mtl], B, acc[mtl][ntl], 0, 0, 0);
        }
      }
    }
    __syncthreads();
  }

  #pragma unroll
  for (int mtl = 0; mtl < 7; ++mtl) {
    const int mt = mh * 7 + mtl;
    #pragma unroll
    for (int ntl = 0; ntl < 2; ++ntl) {
      const int oc = nth * 32 + ntl * 16 + m16;
      const float bb = sB2[oc];
      #pragma unroll
      for (int r = 0; r < 4; ++r) {
        int p = mt * 16 + q * 4 + r;
        if (p < 196)
          h2f[(size_t)n * 12544 + p * 64 + oc] = relu_f(acc[mtl][ntl][r] + bb);
      }
    }
  }
}

// ---------------------------------------------------------------------------
// conv3 (64->128, s2) via 3-split MFMA, ONE sample per block (2048 blocks).
// LDS 20.5 KB; acc 2x4 f32x4 (32 AGPR) -> 4-5 blocks/CU to hide the
// B-fragment L2 latency (R8: 2 blocks/CU left the matrix pipe 71% idle).
// Accumulation order per output (chunk -> tap -> pass) unchanged ->
// bit-identical h3. In-place write after all reads.
// ---------------------------------------------------------------------------
__global__ __launch_bounds__(256, 4) void k_conv3(
    float* hb,
    const unsigned short* __restrict__ w3s,
    const float* __restrict__ b3)
{
  __shared__ __align__(16) short sIn[256 * 40];  // 20,480 B
  __shared__ float sB3[128];
  const int n = blockIdx.x, t = threadIdx.x;
  if (t < 128) sB3[t] = b3[t];
  // zero border rows of the 16x16 haloed image (interior overwritten per chunk)
  for (int bi = t; bi < 60; bi += 256) {
    int p;
    if (bi < 16) p = bi;
    else if (bi < 32) p = 240 + (bi - 16);
    else if (bi < 46) p = (bi - 31) * 16;
    else p = (bi - 45) * 16 + 15;
    unsigned* d = (unsigned*)&sIn[p * 40];
    #pragma unroll
    for (int j = 0; j < 20; ++j) d[j] = 0u;
  }
  const int lane = t & 63, wv = t >> 6;
  const int q = lane >> 4, m16 = lane & 15;
  const int ntp = wv & 1, mh = wv >> 1;   // mh: m-tiles {0,1} / {2,3}
  int abase[2];
  #pragma unroll
  for (int mtl = 0; mtl < 2; ++mtl) {
    int m = (mh * 2 + mtl) * 16 + m16; if (m > 48) m = 48;
    int yy = m / 7, xx = m % 7;
    abase[mtl] = (yy * 32 + xx * 2) * 40 + q * 8;
  }
  f32x4 acc[2][4];
  #pragma unroll
  for (int a = 0; a < 2; ++a)
    #pragma unroll
    for (int b = 0; b < 4; ++b) acc[a][b] = (f32x4)0.f;
  __syncthreads();

  for (int c = 0; c < 8; ++c) {
    __syncthreads();   // prior chunk's A-reads complete before overwrite
    if (t < 196) {
      const int pix = t;
      const int rr = pix / 14 + 1, cc = pix % 14 + 1;
      const float* src = &hb[(size_t)n * 12544 + pix * 64 + c * 8];
      float4 v0 = *(const float4*)src;
      float4 v1 = *(const float4*)(src + 4);
      float vv[8] = {v0.x, v0.y, v0.z, v0.w, v1.x, v1.y, v1.z, v1.w};
      short* drow = &sIn[(rr * 16 + cc) * 40];
      #pragma unroll
      for (int ic = 0; ic < 8; ++ic) {
        float v = vv[ic];
        short h = f2b(v); float hf = s2f(h);
        short mm = f2b(v - hf); float mf = s2f(mm);
        short ll = f2b(v - hf - mf);
        uint2 pk;
        pk.x = (unsigned)(unsigned short)h | ((unsigned)(unsigned short)mm << 16);
        pk.y = (unsigned)(unsigned short)ll;
        *(uint2*)&drow[ic * 4] = pk;
      }
    }
    __syncthreads();

    const unsigned short* wc = w3s + (size_t)c * 110592;
    for (int tap = 0; tap < 9; ++tap) {
      const int toff = ((tap / 3) * 16 + (tap % 3)) * 40;
      bf16x8 A[2];
      #pragma unroll
      for (int mtl = 0; mtl < 2; ++mtl)
        A[mtl] = *(const bf16x8*)&sIn[abase[mtl] + toff];
      #pragma unroll
      for (int pass = 0; pass < 3; ++pass) {
        #pragma unroll
        for (int ntl = 0; ntl < 4; ++ntl) {
          const int oc = ntp * 64 + ntl * 16 + m16;
          bf16x8 B = *(const bf16x8*)&wc[((pass * 9 + tap) * 128 + oc) * 32 + q * 8];
          #pragma unroll
          for (int mtl = 0; mtl < 2; ++mtl)
            acc[mtl][ntl] = __builtin_amdgcn_mfma_f32_16x16x32_bf16(A[mtl], B, acc[mtl][ntl], 0, 0, 0);
        }
      }
    }
  }

  #pragma unroll
  for (int mtl = 0; mtl < 2; ++mtl) {
    const int mt = mh * 2 + mtl;
    #pragma unroll
    for (int ntl = 0; ntl < 4; ++ntl) {
      const int oc = ntp * 64 + ntl * 16 + m16;
      const float bb = sB3[oc];
      #pragma unroll
      for (int r = 0; r < 4; ++r) {
        int m = mt * 16 + q * 4 + r;
        if (m < 49)
          hb[(size_t)n * 12544 + oc * 49 + m] = relu_f(acc[mtl][ntl][r] + bb);
      }
    }
  }
}

// ---------------------------------------------------------------------------
// fc GEMM: rows at stride 12544 (in-place h3), mu/lv, K-split 2 (fp32)
// ---------------------------------------------------------------------------
__global__ __launch_bounds__(256) void k_fc(
    const float* __restrict__ h3,
    const float* __restrict__ w_mu, const float* __restrict__ w_lv,
    float* __restrict__ part)
{
  __shared__ float As[16 * 65];
  __shared__ float Bs[16 * 64];
  const int bx = blockIdx.x, by = blockIdx.y, bz = blockIdx.z;
  const float* __restrict__ W = by ? w_lv : w_mu;
  const int t = threadIdx.x;
  const int tx = t & 15, ty = t >> 4;
  const int m0 = bx * 64;
  const int k0base = bz * 3136;
  const int ar = t >> 2, ac = (t & 3) * 4;
  const int bk = t >> 4, bn = (t & 15) * 4;
  float acc[4][4];
  #pragma unroll
  for (int i = 0; i < 4; ++i)
    #pragma unroll
    for (int j = 0; j < 4; ++j) acc[i][j] = 0.f;

  for (int kt = 0; kt < 196; ++kt) {
    const int k0 = k0base + kt * 16;
    float4 av = *(const float4*)&h3[(size_t)(m0 + ar) * 12544 + k0 + ac];
    float4 bv = *(const float4*)&W[(size_t)(k0 + bk) * 64 + bn];
    __syncthreads();
    As[(ac + 0) * 65 + ar] = av.x;
    As[(ac + 1) * 65 + ar] = av.y;
    As[(ac + 2) * 65 + ar] = av.z;
    As[(ac + 3) * 65 + ar] = av.w;
    *(float4*)&Bs[bk * 64 + bn] = bv;
    __syncthreads();
    #pragma unroll
    for (int kk = 0; kk < 16; ++kk) {
      float a[4], b[4];
      #pragma unroll
      for (int i = 0; i < 4; ++i) a[i] = As[kk * 65 + ty * 4 + i];
      #pragma unroll
      for (int j = 0; j < 4; ++j) b[j] = Bs[kk * 64 + tx * 4 + j];
      #pragma unroll
      for (int i = 0; i < 4; ++i)
        #pragma unroll
        for (int j = 0; j < 4; ++j) acc[i][j] += a[i] * b[j];
    }
  }
  const int slab = by * 2 + bz;
  #pragma unroll
  for (int i = 0; i < 4; ++i)
    #pragma unroll
    for (int j = 0; j < 4; ++j)
      part[(size_t)slab * 131072 + (size_t)(m0 + ty * 4 + i) * 64 + tx * 4 + j] = acc[i][j];
}

// ---------------------------------------------------------------------------
// gate (strict fp32)
// ---------------------------------------------------------------------------
__global__ __launch_bounds__(64) void k_gate(
    const float* __restrict__ part,
    const float* __restrict__ b_mu, const float* __restrict__ b_lv,
    const float* __restrict__ eps,
    const float* __restrict__ gw1, const float* __restrict__ gb1,
    const float* __restrict__ gw2, const float* __restrict__ gb2,
    const float* __restrict__ gw3, const float* __restrict__ gb3,
    float* __restrict__ out, float* __restrict__ zbuf, int* __restrict__ idxbuf)
{
  __shared__ float sZ[64][65];
  __shared__ float sG1[64][65];
  __shared__ float sG2[64][33];
  const int t = threadIdx.x;
  const int m = blockIdx.x * 64 + t;

  for (int k = 0; k < 64; ++k) {
    float mu = b_mu[k] + part[(size_t)m * 64 + k] + part[131072 + (size_t)m * 64 + k];
    float lv = b_lv[k] + part[262144 + (size_t)m * 64 + k] + part[393216 + (size_t)m * 64 + k];
    out[OFF_MU + m * 64 + k] = mu;
    out[OFF_LV + m * 64 + k] = lv;
    float zz = mu + eps[m * 64 + k] * expf(0.5f * lv);
    sZ[t][k] = zz;
    zbuf[m * 64 + k] = zz;
  }
  for (int j = 0; j < 64; ++j) {
    float a = gb1[j];
    for (int k = 0; k < 64; ++k) a += sZ[t][k] * gw1[k * 64 + j];
    sG1[t][j] = relu_f(a);
  }
  for (int j = 0; j < 32; ++j) {
    float a = gb2[j];
    for (int k = 0; k < 64; ++k) a += sG1[t][k] * gw2[k * 32 + j];
    sG2[t][j] = relu_f(a);
  }
  float l[8];
  #pragma unroll
  for (int j = 0; j < 8; ++j) {
    float a = gb3[j];
    for (int k = 0; k < 32; ++k) a += sG2[t][k] * gw3[k * 8 + j];
    l[j] = a;
  }
  float mx = l[0];
  #pragma unroll
  for (int j = 1; j < 8; ++j) mx = fmaxf(mx, l[j]);
  float p[8]; float s = 0.f;
  #pragma unroll
  for (int j = 0; j < 8; ++j) { p[j] = expf(l[j] - mx); s += p[j]; }
  const float inv = 1.f / s;
  float best = -1.f; int bi = 0;
  #pragma unroll
  for (int j = 0; j < 8; ++j) {
    float pj = p[j] * inv;
    out[OFF_PROBS + m * 8 + j] = pj;
    out[OFF_LOGITS + m * 8 + j] = logf(pj + 1e-8f);
    if (pj > best) { best = pj; bi = j; }
  }
  idxbuf[m] = bi;
}

// ---------------------------------------------------------------------------
// one-time decoder weight repack to bf16 (into dead part region).
// ---------------------------------------------------------------------------
__global__ __launch_bounds__(256) void k_prep(
    const float* __restrict__ dw1, const float* __restrict__ dw2,
    unsigned short* __restrict__ w1b, unsigned short* __restrict__ wcb)
{
  const int e = blockIdx.x, job = blockIdx.y, t = threadIdx.x;
  if (job == 0) {
    for (int idx = t; idx < 18432; idx += 256) {
      int tap = idx >> 11, oc = (idx >> 5) & 63, ic = idx & 31;
      w1b[(size_t)e * 18432 + idx] =
          (unsigned short)f2b(dw1[(size_t)e * 18432 + (oc * 32 + ic) * 9 + tap]);
    }
  } else {
    const int par = job - 1, py = par >> 1, px = par & 1;
    for (int v = t; v < 8192; v += 256) {
      int s = v >> 10, oc = (v >> 5) & 31, ic = v & 31;
      int tap = s >> 1, h = s & 1;
      int ty = tap >> 1, tx = tap & 1;
      int icg = h * 32 + ic;
      int ys = (ty == 0) ? 0 : (1 + py);
      int yc = (ty == py) ? 1 : 2;
      int xs = (tx == 0) ? 0 : (1 + px);
      int xc = (tx == px) ? 1 : 2;
      const float* wp = &dw2[(size_t)e * 18432 + (oc * 64 + icg) * 9];
      float a = 0.f;
      for (int ky = ys; ky < ys + yc; ++ky)
        for (int kx = xs; kx < xs + xc; ++kx)
          a += wp[ky * 3 + kx];
      wcb[((size_t)e * 4 + par) * 8192 + v] = (unsigned short)f2b(a);
    }
  }
}

// ---------------------------------------------------------------------------
// decoder fc: z[64] @ d_fc_w[e][64][1568] + b -> hfcb bf16 [n][pix49][ic32]
// ---------------------------------------------------------------------------
__global__ __launch_bounds__(256) void k_dfc(
    const float* __restrict__ zbuf, const int* __restrict__ idxbuf,
    const float* __restrict__ fcw, const float* __restrict__ fcb,
    unsigned* __restrict__ hfcb)
{
  __shared__ float sZ[64];
  __shared__ __align__(16) unsigned short sO[1568];
  const int n = blockIdx.x, t = threadIdx.x;
  const int e = idxbuf[n];
  if (t < 64) sZ[t] = zbuf[n * 64 + t];
  __syncthreads();
  const float* __restrict__ W = fcw + (size_t)e * 100352;
  const int i40 = t, i41 = t + 256;
  const bool v1 = (i41 < 392);
  float a0[4], a1[4];
  {
    float4 b0 = *(const float4*)&fcb[e * 1568 + i40 * 4];
    a0[0] = b0.x; a0[1] = b0.y; a0[2] = b0.z; a0[3] = b0.w;
    if (v1) {
      float4 b1v = *(const float4*)&fcb[e * 1568 + i41 * 4];
      a1[0] = b1v.x; a1[1] = b1v.y; a1[2] = b1v.z; a1[3] = b1v.w;
    } else { a1[0] = a1[1] = a1[2] = a1[3] = 0.f; }
  }
  for (int k = 0; k < 64; ++k) {
    const float zk = sZ[k];
    float4 w0 = *(const float4*)&W[k * 1568 + i40 * 4];
    a0[0] += zk * w0.x; a0[1] += zk * w0.y; a0[2] += zk * w0.z; a0[3] += zk * w0.w;
    if (v1) {
      float4 w1v = *(const float4*)&W[k * 1568 + i41 * 4];
      a1[0] += zk * w1v.x; a1[1] += zk * w1v.y; a1[2] += zk * w1v.z; a1[3] += zk * w1v.w;
    }
  }
  #pragma unroll
  for (int c = 0; c < 4; ++c) {
    int j = i40 * 4 + c;
    int ic = j / 49, p = j % 49;
    sO[p * 32 + ic] = (unsigned short)f2b(a0[c]);
  }
  if (v1) {
    #pragma unroll
    for (int c = 0; c < 4; ++c) {
      int j = i41 * 4 + c;
      int ic = j / 49, p = j % 49;
      sO[p * 32 + ic] = (unsigned short)f2b(a1[c]);
    }
  }
  __syncthreads();
  for (int idx = t; idx < 784; idx += 256)
    hfcb[(size_t)n * 784 + idx] = ((const unsigned*)sO)[idx];
}

// ---------------------------------------------------------------------------
// decoder conv1 via bf16 MFMA implicit GEMM. Output d1o[n][196][64] bf16.
// ---------------------------------------------------------------------------
__global__ __launch_bounds__(256) void k_d1(
    const unsigned* __restrict__ hfcb, const int* __restrict__ idxbuf,
    const unsigned* __restrict__ w1b, const float* __restrict__ b,
    __hip_bfloat16* __restrict__ d1o)
{
  __shared__ __align__(16) short sIn[256 * 40];
  __shared__ __align__(16) short sW[9 * 64 * 32];
  __shared__ float sB[64];

  const int n = blockIdx.x, t = threadIdx.x;
  const int e = idxbuf[n];

  {
    int r = t >> 4, c = t & 15;
    bool inter = (r >= 1 && r <= 14 && c >= 1 && c <= 14);
    int src = inter ? (((r - 1) >> 1) * 7 + ((c - 1) >> 1)) : 0;
    const unsigned* hp = &hfcb[(size_t)n * 784 + src * 16];
    unsigned* dst = (unsigned*)&sIn[t * 40];
    #pragma unroll
    for (int i = 0; i < 16; ++i) dst[i] = inter ? hp[i] : 0u;
  }
  {
    const unsigned* wsrc = w1b + (size_t)e * 9216;
    unsigned* wd = (unsigned*)sW;
    for (int idx = t; idx < 9216; idx += 256) wd[idx] = wsrc[idx];
  }
  if (t < 64) sB[t] = b[e * 64 + t];
  __syncthreads();

  const int wv = t >> 6, lane = t & 63;
  const int q = lane >> 4, m16 = lane & 15;
  const int ocl = wv * 16 + m16;

  f32x4 acc[13];
  int abase[13];
  #pragma unroll
  for (int mt = 0; mt < 13; ++mt) {
    acc[mt] = (f32x4)0.f;
    int p = mt * 16 + m16; if (p > 195) p = 195;
    int y = p / 14, x = p % 14;
    abase[mt] = (y * 16 + x) * 40 + q * 8;
  }

  for (int tap = 0; tap < 9; ++tap) {
    const int ky = tap / 3, kx = tap % 3;
    const int toff = (ky * 16 + kx) * 40;
    bf16x8 bfrag = *(const bf16x8*)&sW[tap * 2048 + ocl * 32 + q * 8];
    #pragma unroll
    for (int mt = 0; mt < 13; ++mt) {
      bf16x8 afrag = *(const bf16x8*)&sIn[abase[mt] + toff];
      acc[mt] = __builtin_amdgcn_mfma_f32_16x16x32_bf16(afrag, bfrag, acc[mt], 0, 0, 0);
    }
  }

  const float bias = sB[ocl];
  #pragma unroll
  for (int mt = 0; mt < 13; ++mt) {
    #pragma unroll
    for (int r = 0; r < 4; ++r) {
      int p = mt * 16 + q * 4 + r;
      if (p < 196) {
        float v = elu_f(acc[mt][r] + bias);
        short s = f2b(v);
        __builtin_memcpy(&d1o[(size_t)n * 12544 + p * 64 + ocl], &s, 2);
      }
    }
  }
}

// ---------------------------------------------------------------------------
// fused decoder conv2+conv3, BOTH on MFMA (parity decomposition).
// ---------------------------------------------------------------------------
__global__ __launch_bounds__(256) void k_d23(
    const unsigned* __restrict__ d1u,
    const int* __restrict__ idxbuf,
    const unsigned* __restrict__ wcb,
    const float* __restrict__ b2,
    const float* __restrict__ w3, const float* __restrict__ b3,
    float* __restrict__ out)
{
  __shared__ __align__(16) short sD1[256 * 72];
  __shared__ __align__(16) short sU[8192];
  __shared__ __align__(16) short sW3b[512];
  __shared__ float sC[196 * 9];
  __shared__ float sB2[32];

  const int n = blockIdx.x, t = threadIdx.x;
  const int e = idxbuf[n];

  {
    unsigned* d = (unsigned*)sD1;
    for (int idx = t; idx < 9216; idx += 256) d[idx] = 0u;
  }
  __syncthreads();
  {
    unsigned* d = (unsigned*)sD1;
    for (int idx = t; idx < 6272; idx += 256) {
      unsigned v = d1u[(size_t)n * 6272 + idx];
      int p = idx >> 5, icp = idx & 31;
      int r = p / 14, c = p % 14;
      d[((r + 1) * 16 + (c + 1)) * 36 + icp] = v;
    }
  }
  for (int j = t; j < 512; j += 256) {
    int nn = j >> 5, k = j & 31;
    sW3b[nn * 32 + k] = (nn < 9) ? f2b(w3[e * 288 + k * 9 + nn]) : (short)0;
  }
  if (t < 32) sB2[t] = b2[e * 32 + t];
  __syncthreads();

  const int wv = t >> 6, lane = t & 63;
  const int q = lane >> 4, m16 = lane & 15;
  const int nt = wv & 1, mh = wv >> 1;
  const int ocl = nt * 16 + m16;
  const int nm = (mh == 0) ? 7 : 6;

  const bf16x8 b3f = *(const bf16x8*)&sW3b[m16 * 32 + q * 8];

  int mt3[4], ab3[4];
  const int nmt3 = (wv == 0) ? 4 : 3;
  #pragma unroll
  for (int i = 0; i < 4; ++i) {
    int mt = wv + 4 * i; if (mt > 12) mt = 12;
    mt3[i] = mt;
    int p = mt * 16 + m16; if (p > 195) p = 195;
    ab3[i] = p * 40 + q * 8;
  }

  int PY[4], PX[4];
  #pragma unroll
  for (int g = 0; g < 4; ++g) {
    int P = t + 256 * g;
    PY[g] = (P < 784) ? P / 28 : -100;
    PX[g] = (P < 784) ? P % 28 : 0;
  }
  float racc[4] = {0.f, 0.f, 0.f, 0.f};

  int ab0[7];
  #pragma unroll
  for (int im = 0; im < 7; ++im) {
    int mt = mh + 2 * im;
    int p = mt * 16 + m16; if (p > 195) p = 195;
    int a = p / 14, bb = p % 14;
    ab0[im] = (a * 16 + bb) * 72 + q * 8;
  }

  for (int par = 0; par < 4; ++par) {
    const int py = par >> 1, px = par & 1;

    {
      const unsigned* wc = wcb + ((size_t)e * 4 + par) * 4096;
      unsigned* du = (unsigned*)sU;
      for (int v = t; v < 4096; v += 256) du[v] = wc[v];
    }
    __syncthreads();

    f32x4 acc[7];
    #pragma unroll
    for (int im = 0; im < 7; ++im) acc[im] = (f32x4)0.f;
    const int pbase = (py * 16 + px) * 72;
    for (int s = 0; s < 8; ++s) {
      int tap = s >> 1, h = s & 1;
      int ty = tap >> 1, tx = tap & 1;
      int toff = pbase + (ty * 16 + tx) * 72 + h * 32;
      bf16x8 bfrag = *(const bf16x8*)&sU[s * 1024 + ocl * 32 + q * 8];
      #pragma unroll
      for (int im = 0; im < 7; ++im) {
        if (im < nm) {
          bf16x8 afrag = *(const bf16x8*)&sD1[ab0[im] + toff];
          acc[im] = __builtin_amdgcn_mfma_f32_16x16x32_bf16(afrag, bfrag, acc[im], 0, 0, 0);
        }
      }
    }
    __syncthreads();

    {
      const float bias = sB2[ocl];
      #pragma unroll
      for (int im = 0; im < 7; ++im) {
        if (im < nm) {
          int mt = mh + 2 * im;
          #pragma unroll
          for (int r = 0; r < 4; ++r) {
            int p = mt * 16 + q * 4 + r;
            if (p < 196) sU[p * 40 + ocl] = f2b(elu_f(acc[im][r] + bias));
          }
        }
      }
    }
    __syncthreads();

    #pragma unroll
    for (int i = 0; i < 4; ++i) {
      if (i < nmt3) {
        bf16x8 af = *(const bf16x8*)&sU[ab3[i]];
        f32x4 a3 = (f32x4)0.f;
        a3 = __builtin_amdgcn_mfma_f32_16x16x32_bf16(af, b3f, a3, 0, 0, 0);
        if (m16 < 9) {
          #pragma unroll
          for (int r = 0; r < 4; ++r) {
            int p = mt3[i] * 16 + q * 4 + r;
            if (p < 196) sC[p * 9 + m16] = a3[r];
          }
        }
      }
    }
    __syncthreads();

    #pragma unroll
    for (int g = 0; g < 4; ++g) {
      const int Y = PY[g], X = PX[g];
      if (Y < 0) continue;
      int RS[2]; int nr = 0;
      if ((Y & 1) == py) { RS[0] = Y; nr = 1; }
      else { if (Y > 0) RS[nr++] = Y - 1; if (Y < 27) RS[nr++] = Y + 1; }
      int CS[2]; int nc = 0;
      if ((X & 1) == px) { CS[0] = X; nc = 1; }
      else { if (X > 0) CS[nc++] = X - 1; if (X < 27) CS[nc++] = X + 1; }
      float s = 0.f;
      for (int ir = 0; ir < nr; ++ir) {
        const int R = RS[ir];
        const int a = (R - py) >> 1, ky = R - Y + 1;
        for (int jc = 0; jc < nc; ++jc) {
          const int C = CS[jc];
          const int bq = (C - px) >> 1, kx = C - X + 1;
          s += sC[(a * 14 + bq) * 9 + ky * 3 + kx];
        }
      }
      racc[g] += s;
    }
    __syncthreads();
  }

  const float b3e = b3[e];
  #pragma unroll
  for (int g = 0; g < 4; ++g) {
    int P = t + 256 * g;
    if (P < 784)
      out[OFF_RECON + (size_t)n * 784 + P] = 1.f / (1.f + expf(-(racc[g] + b3e)));
  }
}

// ---------------------------------------------------------------------------
extern "C" void kernel_launch(void* const* d_in, const int* in_sizes, int n_in,
                              void* d_out, int out_size, void* d_ws, size_t ws_size,
                              hipStream_t stream) {
  const float* x    = (const float*)d_in[0];
  const float* eps  = (const float*)d_in[1];
  const float* ew1  = (const float*)d_in[2];
  const float* eb1  = (const float*)d_in[3];
  const float* ew2  = (const float*)d_in[4];
  const float* eb2  = (const float*)d_in[5];
  const float* ew3  = (const float*)d_in[6];
  const float* eb3  = (const float*)d_in[7];
  const float* wmu  = (const float*)d_in[8];
  const float* bmu  = (const float*)d_in[9];
  const float* wlv  = (const float*)d_in[10];
  const float* blv  = (const float*)d_in[11];
  const float* gw1  = (const float*)d_in[12];
  const float* gb1  = (const float*)d_in[13];
  const float* gw2  = (const float*)d_in[14];
  const float* gb2  = (const float*)d_in[15];
  const float* gw3  = (const float*)d_in[16];
  const float* gb3  = (const float*)d_in[17];
  const float* dfcw = (const float*)d_in[18];
  const float* dfcb = (const float*)d_in[19];
  const float* dw1  = (const float*)d_in[20];
  const float* db1  = (const float*)d_in[21];
  const float* dw2  = (const float*)d_in[22];
  const float* db2  = (const float*)d_in[23];
  const float* dw3  = (const float*)d_in[24];
  const float* db3  = (const float*)d_in[25];

  float* out = (float*)d_out;
  float* ws  = (float*)d_ws;

  float* U    = ws + WS_U;
  float* part = ws + WS_PART;
  float* zb   = ws + WS_Z;
  int*   idx  = (int*)(ws + WS_IDX);
  unsigned* hfcb = (unsigned*)(U + HFC_OFF);
  __hip_bfloat16* d1o = (__hip_bfloat16*)(U + D1O_OFF);
  unsigned short* w1b = (unsigned short*)(part + W1B_OFF);
  unsigned short* wcb = (unsigned short*)(part + WCB_OFF);
  unsigned short* w2s = (unsigned short*)(ws + WS_WENC + W2S_OFF);
  unsigned short* w3s = (unsigned short*)(ws + WS_WENC + W3S_OFF);

  k_prep_enc<<<1080, 256, 0, stream>>>(ew2, ew3, w2s, w3s);
  k_conv12<<<NB, 256, 0, stream>>>(x, ew1, eb1, eb2, w2s, U);
  k_conv3 <<<NB, 256, 0, stream>>>(U, w3s, eb3);
  k_fc    <<<dim3(32, 2, 2), 256, 0, stream>>>(U, wmu, wlv, part);
  k_gate  <<<32, 64, 0, stream>>>(part, bmu, blv, eps, gw1, gb1, gw2, gb2, gw3, gb3,
                                  out, zb, idx);
  k_prep  <<<dim3(8, 5), 256, 0, stream>>>(dw1, dw2, w1b, wcb);
  k_dfc   <<<NB, 256, 0, stream>>>(zb, idx, dfcw, dfcb, hfcb);
  k_d1    <<<NB, 256, 0, stream>>>(hfcb, idx, (const unsigned*)w1b, db1, d1o);
  k_d23   <<<NB, 256, 0, stream>>>((const unsigned*)d1o, idx, (const unsigned*)wcb,
                                   db2, dw3, db3, out);
}

// Round 10
// 1092.810 us; speedup vs baseline: 1.1732x; 1.1732x over previous
//
#include <hip/hip_runtime.h>
#include <hip/hip_bf16.h>

// ---------------------------------------------------------------------------
// VAE + supervised MoE forward, MI355X.
//   k_prep_enc: one-time 3-way bf16 split of encoder conv2/conv3 weights
//   k_conv12 : conv1 fp32 exact + conv2 via 3-split bf16 MFMA -> h2f fp32
//   k_conv3  : 1-sample blocks (20.5KB LDS -> ~4 blocks/CU), wave = oc-quarter
//              covering ALL 4 m-tiles (B:MFMA = 1:4 — R9's wave map doubled
//              B traffic and regressed); 3-split MFMA; h3 in-place
//   k_fc     : h3(stride 12544) @ [w_mu|w_lv], K-split 2 (fp32)
//   k_gate   : mu/lv, z, gating MLP, softmax, argmax (strict fp32)
//   k_prep   : decoder weight repack to bf16 (into dead part region)
//   k_dfc    : z @ d_fc_w[e] + b -> hfcb bf16 (float4 weight stream)
//   k_d1     : up2+conv(32->64)+elu via bf16 MFMA -> d1o
//   k_d23    : up2+conv(64->32)+elu fused conv(32->1)+sigmoid, all on MFMA
// Only the argmax expert is decoded per sample. Gating stays fp32-accurate.
// ---------------------------------------------------------------------------

#define NB 2048

typedef short bf16x8 __attribute__((ext_vector_type(8)));
typedef float f32x4  __attribute__((ext_vector_type(4)));

static constexpr int OFF_RECON  = 0;
static constexpr int OFF_MU     = 1605632;
static constexpr int OFF_LV     = 1736704;
static constexpr int OFF_LOGITS = 1867776;
static constexpr int OFF_PROBS  = 1884160;

// workspace layout (float units)
static constexpr size_t WS_U    = 0;         // 25,690,112 fl
static constexpr size_t WS_PART = 25690112;  // 524,288 fl
static constexpr size_t WS_Z    = 26214400;  // 131,072 fl
static constexpr size_t WS_IDX  = 26345472;  // 2,048 ints = 512 fl
static constexpr size_t WS_WENC = 26345984;  // encoder split weights
static constexpr size_t W2S_OFF = 0;         // 110,592 fl
static constexpr size_t W3S_OFF = 110592;    // 442,368 fl
static constexpr size_t HFC_OFF = 0;         // hfcb bf16 [n][49][32] in U
static constexpr size_t D1O_OFF = 3211264;   // d1o bf16 [n][196][64] in U
static constexpr size_t W1B_OFF = 0;         // in part region
static constexpr size_t WCB_OFF = 73728;     // in part region

__device__ __forceinline__ float relu_f(float v) { return v > 0.f ? v : 0.f; }
__device__ __forceinline__ float elu_f(float v)  { return v > 0.f ? v : expm1f(v); }
__device__ __forceinline__ short f2b(float v) {
  __hip_bfloat16 h = __float2bfloat16(v);
  short s; __builtin_memcpy(&s, &h, 2); return s;
}
__device__ __forceinline__ float s2f(short s) {
  unsigned v = ((unsigned)(unsigned short)s) << 16;
  float f; __builtin_memcpy(&f, &v, 4); return f;
}
__device__ __forceinline__ float blo(unsigned u) {
  unsigned v = u << 16; float f; __builtin_memcpy(&f, &v, 4); return f;
}
__device__ __forceinline__ float bhi(unsigned u) {
  unsigned v = u & 0xffff0000u; float f; __builtin_memcpy(&f, &v, 4); return f;
}

// ---------------------------------------------------------------------------
// one-time encoder weight 3-split (h,m,l), slot-duplicated x4 along k.
// ---------------------------------------------------------------------------
__global__ __launch_bounds__(256) void k_prep_enc(
    const float* __restrict__ ew2, const float* __restrict__ ew3,
    unsigned short* __restrict__ w2s, unsigned short* __restrict__ w3s)
{
  const int u = blockIdx.x * 256 + threadIdx.x;
  if (u >= 276480) return;
  float w; uint2* dst; int pass;
  if (u < 55296) {
    int chunk = u / 13824, r = u % 13824;
    pass = r / 4608; int r2 = r % 4608;
    int tap = r2 / 512, r3 = r2 % 512;
    int oc = r3 / 8, ic = r3 % 8;
    w = ew2[oc * 288 + (chunk * 8 + ic) * 9 + tap];
    dst = (uint2*)w2s + u;
  } else {
    int u2 = u - 55296;
    int chunk = u2 / 27648, r = u2 % 27648;
    pass = r / 9216; int r2 = r % 9216;
    int tap = r2 / 1024, r3 = r2 % 1024;
    int oc = r3 / 8, ic = r3 % 8;
    w = ew3[oc * 576 + (chunk * 8 + ic) * 9 + tap];
    dst = (uint2*)w3s + u2;
  }
  short h = f2b(w); float hf = s2f(h);
  short mm = f2b(w - hf); float mf = s2f(mm);
  short ll = f2b(w - hf - mf);
  short val = (pass == 0) ? h : (pass == 1) ? mm : ll;
  unsigned vv = (unsigned)(unsigned short)val | ((unsigned)(unsigned short)val << 16);
  uint2 pk; pk.x = vv; pk.y = vv;
  *dst = pk;
}

// ---------------------------------------------------------------------------
// conv1 (1->32, exact fp32) fused with conv2 (32->64, s2) via 3-split MFMA.
// ---------------------------------------------------------------------------
__global__ __launch_bounds__(256, 2) void k_conv12(
    const float* __restrict__ x,
    const float* __restrict__ w1, const float* __restrict__ b1,
    const float* __restrict__ b2g, const unsigned short* __restrict__ w2s,
    float* __restrict__ h2f)
{
  __shared__ float sX[900];
  __shared__ float sB2[64];
  __shared__ __align__(16) short sH[900 * 40];

  const int n = blockIdx.x, t = threadIdx.x;

  for (int idx = t; idx < 900; idx += 256) {
    int yy = idx / 30, xx = idx % 30;
    float v = 0.f;
    if (yy >= 1 && yy <= 28 && xx >= 1 && xx <= 28)
      v = x[n * 784 + (yy - 1) * 28 + (xx - 1)];
    sX[idx] = v;
  }
  if (t < 64) sB2[t] = b2g[t];
  for (int bi = t; bi < 116; bi += 256) {
    int p;
    if (bi < 30) p = bi;
    else if (bi < 60) p = 870 + (bi - 30);
    else if (bi < 88) p = (bi - 59) * 30;
    else p = (bi - 87) * 30 + 29;
    unsigned* d = (unsigned*)&sH[p * 40];
    #pragma unroll
    for (int j = 0; j < 20; ++j) d[j] = 0u;
  }
  __syncthreads();

  float xw[4][9];
  int hp[4]; bool pvld[4];
  #pragma unroll
  for (int i = 0; i < 4; ++i) {
    int p = t + 256 * i;
    pvld[i] = (p < 784);
    int yy = pvld[i] ? p / 28 : 0, xx = pvld[i] ? p % 28 : 0;
    hp[i] = (yy + 1) * 30 + xx + 1;
    #pragma unroll
    for (int k = 0; k < 9; ++k)
      xw[i][k] = sX[(yy + k / 3) * 30 + xx + (k % 3)];
  }

  const int lane = t & 63, wv = t >> 6;
  const int q = lane >> 4, m16 = lane & 15;
  const int nth = wv & 1, mh = wv >> 1;

  int abase[7];
  #pragma unroll
  for (int mtl = 0; mtl < 7; ++mtl) {
    int m = (mh * 7 + mtl) * 16 + m16; if (m > 195) m = 195;
    int yy = m / 14, xx = m % 14;
    abase[mtl] = (yy * 60 + xx * 2) * 40 + q * 8;
  }
  f32x4 acc[7][2];
  #pragma unroll
  for (int a = 0; a < 7; ++a) { acc[a][0] = (f32x4)0.f; acc[a][1] = (f32x4)0.f; }

  for (int c = 0; c < 4; ++c) {
    #pragma unroll
    for (int o = 0; o < 8; ++o) {
      const int oc = c * 8 + o;
      float wr[9];
      #pragma unroll
      for (int k = 0; k < 9; ++k) wr[k] = w1[oc * 9 + k];
      const float bb = b1[oc];
      #pragma unroll
      for (int i = 0; i < 4; ++i) if (pvld[i]) {
        float v = bb;
        #pragma unroll
        for (int k = 0; k < 9; ++k) v += xw[i][k] * wr[k];
        v = relu_f(v);
        short h = f2b(v); float hf = s2f(h);
        short mm = f2b(v - hf); float mf = s2f(mm);
        short ll = f2b(v - hf - mf);
        uint2 pk;
        pk.x = (unsigned)(unsigned short)h | ((unsigned)(unsigned short)mm << 16);
        pk.y = (unsigned)(unsigned short)ll;
        *(uint2*)&sH[hp[i] * 40 + o * 4] = pk;
      }
    }
    __syncthreads();

    const unsigned short* wb = w2s + (size_t)c * 55296;
    for (int tap = 0; tap < 9; ++tap) {
      const int toff = ((tap / 3) * 30 + (tap % 3)) * 40;
      bf16x8 A[7];
      #pragma unroll
      for (int mtl = 0; mtl < 7; ++mtl)
        A[mtl] = *(const bf16x8*)&sH[abase[mtl] + toff];
      #pragma unroll
      for (int pass = 0; pass < 3; ++pass) {
        #pragma unroll
        for (int ntl = 0; ntl < 2; ++ntl) {
          const int ocl = nth * 32 + ntl * 16 + m16;
          bf16x8 B = *(const bf16x8*)&wb[((pass * 9 + tap) * 64 + ocl) * 32 + q * 8];
          #pragma unroll
          for (int mtl = 0; mtl < 7; ++mtl)
            acc[mtl][ntl] = __builtin_amdgcn_mfma_f32_16x16x32_bf16(A[mtl], B, acc[mtl][ntl], 0, 0, 0);
        }
      }
    }
    __syncthreads();
  }

  #pragma unroll
  for (int mtl = 0; mtl < 7; ++mtl) {
    const int mt = mh * 7 + mtl;
    #pragma unroll
    for (int ntl = 0; ntl < 2; ++ntl) {
      const int oc = nth * 32 + ntl * 16 + m16;
      const float bb = sB2[oc];
      #pragma unroll
      for (int r = 0; r < 4; ++r) {
        int p = mt * 16 + q * 4 + r;
        if (p < 196)
          h2f[(size_t)n * 12544 + p * 64 + oc] = relu_f(acc[mtl][ntl][r] + bb);
      }
    }
  }
}

// ---------------------------------------------------------------------------
// conv3 (64->128, s2) via 3-split MFMA, ONE sample per block (2048 blocks).
// LDS 20.5 KB (-> ~4 blocks/CU). Wave = oc-quarter (32 oc, ntl 2), covering
// ALL 4 m-tiles: per B load 4 MFMAs (R9's map was 1:2 -> double B traffic,
// regressed). acc[4][2] = 32 AGPR. Accumulation order per output
// (chunk -> tap -> pass) unchanged -> bit-identical h3. In-place write.
// ---------------------------------------------------------------------------
__global__ __launch_bounds__(256, 4) void k_conv3(
    float* hb,
    const unsigned short* __restrict__ w3s,
    const float* __restrict__ b3)
{
  __shared__ __align__(16) short sIn[256 * 40];  // 20,480 B
  __shared__ float sB3[128];
  const int n = blockIdx.x, t = threadIdx.x;
  if (t < 128) sB3[t] = b3[t];
  // zero border rows of the 16x16 haloed image (interior overwritten per chunk)
  for (int bi = t; bi < 60; bi += 256) {
    int p;
    if (bi < 16) p = bi;
    else if (bi < 32) p = 240 + (bi - 16);
    else if (bi < 46) p = (bi - 31) * 16;
    else p = (bi - 45) * 16 + 15;
    unsigned* d = (unsigned*)&sIn[p * 40];
    #pragma unroll
    for (int j = 0; j < 20; ++j) d[j] = 0u;
  }
  const int lane = t & 63, wv = t >> 6;   // wv = oc-quarter
  const int q = lane >> 4, m16 = lane & 15;
  int abase[4];
  #pragma unroll
  for (int mtl = 0; mtl < 4; ++mtl) {
    int m = mtl * 16 + m16; if (m > 48) m = 48;
    int yy = m / 7, xx = m % 7;
    abase[mtl] = (yy * 32 + xx * 2) * 40 + q * 8;
  }
  f32x4 acc[4][2];
  #pragma unroll
  for (int a = 0; a < 4; ++a) { acc[a][0] = (f32x4)0.f; acc[a][1] = (f32x4)0.f; }
  __syncthreads();

  for (int c = 0; c < 8; ++c) {
    __syncthreads();   // prior chunk's A-reads complete before overwrite
    if (t < 196) {
      const int pix = t;
      const int rr = pix / 14 + 1, cc = pix % 14 + 1;
      const float* src = &hb[(size_t)n * 12544 + pix * 64 + c * 8];
      float4 v0 = *(const float4*)src;
      float4 v1 = *(const float4*)(src + 4);
      float vv[8] = {v0.x, v0.y, v0.z, v0.w, v1.x, v1.y, v1.z, v1.w};
      short* drow = &sIn[(rr * 16 + cc) * 40];
      #pragma unroll
      for (int ic = 0; ic < 8; ++ic) {
        float v = vv[ic];
        short h = f2b(v); float hf = s2f(h);
        short mm = f2b(v - hf); float mf = s2f(mm);
        short ll = f2b(v - hf - mf);
        uint2 pk;
        pk.x = (unsigned)(unsigned short)h | ((unsigned)(unsigned short)mm << 16);
        pk.y = (unsigned)(unsigned short)ll;
        *(uint2*)&drow[ic * 4] = pk;
      }
    }
    __syncthreads();

    const unsigned short* wc = w3s + (size_t)c * 110592;
    for (int tap = 0; tap < 9; ++tap) {
      const int toff = ((tap / 3) * 16 + (tap % 3)) * 40;
      bf16x8 A[4];
      #pragma unroll
      for (int mtl = 0; mtl < 4; ++mtl)
        A[mtl] = *(const bf16x8*)&sIn[abase[mtl] + toff];
      #pragma unroll
      for (int pass = 0; pass < 3; ++pass) {
        #pragma unroll
        for (int ntl = 0; ntl < 2; ++ntl) {
          const int oc = wv * 32 + ntl * 16 + m16;
          bf16x8 B = *(const bf16x8*)&wc[((pass * 9 + tap) * 128 + oc) * 32 + q * 8];
          #pragma unroll
          for (int mtl = 0; mtl < 4; ++mtl)
            acc[mtl][ntl] = __builtin_amdgcn_mfma_f32_16x16x32_bf16(A[mtl], B, acc[mtl][ntl], 0, 0, 0);
        }
      }
    }
  }

  #pragma unroll
  for (int mtl = 0; mtl < 4; ++mtl) {
    #pragma unroll
    for (int ntl = 0; ntl < 2; ++ntl) {
      const int oc = wv * 32 + ntl * 16 + m16;
      const float bb = sB3[oc];
      #pragma unroll
      for (int r = 0; r < 4; ++r) {
        int m = mtl * 16 + q * 4 + r;
        if (m < 49)
          hb[(size_t)n * 12544 + oc * 49 + m] = relu_f(acc[mtl][ntl][r] + bb);
      }
    }
  }
}

// ---------------------------------------------------------------------------
// fc GEMM: rows at stride 12544 (in-place h3), mu/lv, K-split 2 (fp32)
// ---------------------------------------------------------------------------
__global__ __launch_bounds__(256) void k_fc(
    const float* __restrict__ h3,
    const float* __restrict__ w_mu, const float* __restrict__ w_lv,
    float* __restrict__ part)
{
  __shared__ float As[16 * 65];
  __shared__ float Bs[16 * 64];
  const int bx = blockIdx.x, by = blockIdx.y, bz = blockIdx.z;
  const float* __restrict__ W = by ? w_lv : w_mu;
  const int t = threadIdx.x;
  const int tx = t & 15, ty = t >> 4;
  const int m0 = bx * 64;
  const int k0base = bz * 3136;
  const int ar = t >> 2, ac = (t & 3) * 4;
  const int bk = t >> 4, bn = (t & 15) * 4;
  float acc[4][4];
  #pragma unroll
  for (int i = 0; i < 4; ++i)
    #pragma unroll
    for (int j = 0; j < 4; ++j) acc[i][j] = 0.f;

  for (int kt = 0; kt < 196; ++kt) {
    const int k0 = k0base + kt * 16;
    float4 av = *(const float4*)&h3[(size_t)(m0 + ar) * 12544 + k0 + ac];
    float4 bv = *(const float4*)&W[(size_t)(k0 + bk) * 64 + bn];
    __syncthreads();
    As[(ac + 0) * 65 + ar] = av.x;
    As[(ac + 1) * 65 + ar] = av.y;
    As[(ac + 2) * 65 + ar] = av.z;
    As[(ac + 3) * 65 + ar] = av.w;
    *(float4*)&Bs[bk * 64 + bn] = bv;
    __syncthreads();
    #pragma unroll
    for (int kk = 0; kk < 16; ++kk) {
      float a[4], b[4];
      #pragma unroll
      for (int i = 0; i < 4; ++i) a[i] = As[kk * 65 + ty * 4 + i];
      #pragma unroll
      for (int j = 0; j < 4; ++j) b[j] = Bs[kk * 64 + tx * 4 + j];
      #pragma unroll
      for (int i = 0; i < 4; ++i)
        #pragma unroll
        for (int j = 0; j < 4; ++j) acc[i][j] += a[i] * b[j];
    }
  }
  const int slab = by * 2 + bz;
  #pragma unroll
  for (int i = 0; i < 4; ++i)
    #pragma unroll
    for (int j = 0; j < 4; ++j)
      part[(size_t)slab * 131072 + (size_t)(m0 + ty * 4 + i) * 64 + tx * 4 + j] = acc[i][j];
}

// ---------------------------------------------------------------------------
// gate (strict fp32)
// ---------------------------------------------------------------------------
__global__ __launch_bounds__(64) void k_gate(
    const float* __restrict__ part,
    const float* __restrict__ b_mu, const float* __restrict__ b_lv,
    const float* __restrict__ eps,
    const float* __restrict__ gw1, const float* __restrict__ gb1,
    const float* __restrict__ gw2, const float* __restrict__ gb2,
    const float* __restrict__ gw3, const float* __restrict__ gb3,
    float* __restrict__ out, float* __restrict__ zbuf, int* __restrict__ idxbuf)
{
  __shared__ float sZ[64][65];
  __shared__ float sG1[64][65];
  __shared__ float sG2[64][33];
  const int t = threadIdx.x;
  const int m = blockIdx.x * 64 + t;

  for (int k = 0; k < 64; ++k) {
    float mu = b_mu[k] + part[(size_t)m * 64 + k] + part[131072 + (size_t)m * 64 + k];
    float lv = b_lv[k] + part[262144 + (size_t)m * 64 + k] + part[393216 + (size_t)m * 64 + k];
    out[OFF_MU + m * 64 + k] = mu;
    out[OFF_LV + m * 64 + k] = lv;
    float zz = mu + eps[m * 64 + k] * expf(0.5f * lv);
    sZ[t][k] = zz;
    zbuf[m * 64 + k] = zz;
  }
  for (int j = 0; j < 64; ++j) {
    float a = gb1[j];
    for (int k = 0; k < 64; ++k) a += sZ[t][k] * gw1[k * 64 + j];
    sG1[t][j] = relu_f(a);
  }
  for (int j = 0; j < 32; ++j) {
    float a = gb2[j];
    for (int k = 0; k < 64; ++k) a += sG1[t][k] * gw2[k * 32 + j];
    sG2[t][j] = relu_f(a);
  }
  float l[8];
  #pragma unroll
  for (int j = 0; j < 8; ++j) {
    float a = gb3[j];
    for (int k = 0; k < 32; ++k) a += sG2[t][k] * gw3[k * 8 + j];
    l[j] = a;
  }
  float mx = l[0];
  #pragma unroll
  for (int j = 1; j < 8; ++j) mx = fmaxf(mx, l[j]);
  float p[8]; float s = 0.f;
  #pragma unroll
  for (int j = 0; j < 8; ++j) { p[j] = expf(l[j] - mx); s += p[j]; }
  const float inv = 1.f / s;
  float best = -1.f; int bi = 0;
  #pragma unroll
  for (int j = 0; j < 8; ++j) {
    float pj = p[j] * inv;
    out[OFF_PROBS + m * 8 + j] = pj;
    out[OFF_LOGITS + m * 8 + j] = logf(pj + 1e-8f);
    if (pj > best) { best = pj; bi = j; }
  }
  idxbuf[m] = bi;
}

// ---------------------------------------------------------------------------
// one-time decoder weight repack to bf16 (into dead part region).
// ---------------------------------------------------------------------------
__global__ __launch_bounds__(256) void k_prep(
    const float* __restrict__ dw1, const float* __restrict__ dw2,
    unsigned short* __restrict__ w1b, unsigned short* __restrict__ wcb)
{
  const int e = blockIdx.x, job = blockIdx.y, t = threadIdx.x;
  if (job == 0) {
    for (int idx = t; idx < 18432; idx += 256) {
      int tap = idx >> 11, oc = (idx >> 5) & 63, ic = idx & 31;
      w1b[(size_t)e * 18432 + idx] =
          (unsigned short)f2b(dw1[(size_t)e * 18432 + (oc * 32 + ic) * 9 + tap]);
    }
  } else {
    const int par = job - 1, py = par >> 1, px = par & 1;
    for (int v = t; v < 8192; v += 256) {
      int s = v >> 10, oc = (v >> 5) & 31, ic = v & 31;
      int tap = s >> 1, h = s & 1;
      int ty = tap >> 1, tx = tap & 1;
      int icg = h * 32 + ic;
      int ys = (ty == 0) ? 0 : (1 + py);
      int yc = (ty == py) ? 1 : 2;
      int xs = (tx == 0) ? 0 : (1 + px);
      int xc = (tx == px) ? 1 : 2;
      const float* wp = &dw2[(size_t)e * 18432 + (oc * 64 + icg) * 9];
      float a = 0.f;
      for (int ky = ys; ky < ys + yc; ++ky)
        for (int kx = xs; kx < xs + xc; ++kx)
          a += wp[ky * 3 + kx];
      wcb[((size_t)e * 4 + par) * 8192 + v] = (unsigned short)f2b(a);
    }
  }
}

// ---------------------------------------------------------------------------
// decoder fc: z[64] @ d_fc_w[e][64][1568] + b -> hfcb bf16 [n][pix49][ic32]
// ---------------------------------------------------------------------------
__global__ __launch_bounds__(256) void k_dfc(
    const float* __restrict__ zbuf, const int* __restrict__ idxbuf,
    const float* __restrict__ fcw, const float* __restrict__ fcb,
    unsigned* __restrict__ hfcb)
{
  __shared__ float sZ[64];
  __shared__ __align__(16) unsigned short sO[1568];
  const int n = blockIdx.x, t = threadIdx.x;
  const int e = idxbuf[n];
  if (t < 64) sZ[t] = zbuf[n * 64 + t];
  __syncthreads();
  const float* __restrict__ W = fcw + (size_t)e * 100352;
  const int i40 = t, i41 = t + 256;
  const bool v1 = (i41 < 392);
  float a0[4], a1[4];
  {
    float4 b0 = *(const float4*)&fcb[e * 1568 + i40 * 4];
    a0[0] = b0.x; a0[1] = b0.y; a0[2] = b0.z; a0[3] = b0.w;
    if (v1) {
      float4 b1v = *(const float4*)&fcb[e * 1568 + i41 * 4];
      a1[0] = b1v.x; a1[1] = b1v.y; a1[2] = b1v.z; a1[3] = b1v.w;
    } else { a1[0] = a1[1] = a1[2] = a1[3] = 0.f; }
  }
  for (int k = 0; k < 64; ++k) {
    const float zk = sZ[k];
    float4 w0 = *(const float4*)&W[k * 1568 + i40 * 4];
    a0[0] += zk * w0.x; a0[1] += zk * w0.y; a0[2] += zk * w0.z; a0[3] += zk * w0.w;
    if (v1) {
      float4 w1v = *(const float4*)&W[k * 1568 + i41 * 4];
      a1[0] += zk * w1v.x; a1[1] += zk * w1v.y; a1[2] += zk * w1v.z; a1[3] += zk * w1v.w;
    }
  }
  #pragma unroll
  for (int c = 0; c < 4; ++c) {
    int j = i40 * 4 + c;
    int ic = j / 49, p = j % 49;
    sO[p * 32 + ic] = (unsigned short)f2b(a0[c]);
  }
  if (v1) {
    #pragma unroll
    for (int c = 0; c < 4; ++c) {
      int j = i41 * 4 + c;
      int ic = j / 49, p = j % 49;
      sO[p * 32 + ic] = (unsigned short)f2b(a1[c]);
    }
  }
  __syncthreads();
  for (int idx = t; idx < 784; idx += 256)
    hfcb[(size_t)n * 784 + idx] = ((const unsigned*)sO)[idx];
}

// ---------------------------------------------------------------------------
// decoder conv1 via bf16 MFMA implicit GEMM. Output d1o[n][196][64] bf16.
// ---------------------------------------------------------------------------
__global__ __launch_bounds__(256) void k_d1(
    const unsigned* __restrict__ hfcb, const int* __restrict__ idxbuf,
    const unsigned* __restrict__ w1b, const float* __restrict__ b,
    __hip_bfloat16* __restrict__ d1o)
{
  __shared__ __align__(16) short sIn[256 * 40];
  __shared__ __align__(16) short sW[9 * 64 * 32];
  __shared__ float sB[64];

  const int n = blockIdx.x, t = threadIdx.x;
  const int e = idxbuf[n];

  {
    int r = t >> 4, c = t & 15;
    bool inter = (r >= 1 && r <= 14 && c >= 1 && c <= 14);
    int src = inter ? (((r - 1) >> 1) * 7 + ((c - 1) >> 1)) : 0;
    const unsigned* hp = &hfcb[(size_t)n * 784 + src * 16];
    unsigned* dst = (unsigned*)&sIn[t * 40];
    #pragma unroll
    for (int i = 0; i < 16; ++i) dst[i] = inter ? hp[i] : 0u;
  }
  {
    const unsigned* wsrc = w1b + (size_t)e * 9216;
    unsigned* wd = (unsigned*)sW;
    for (int idx = t; idx < 9216; idx += 256) wd[idx] = wsrc[idx];
  }
  if (t < 64) sB[t] = b[e * 64 + t];
  __syncthreads();

  const int wv = t >> 6, lane = t & 63;
  const int q = lane >> 4, m16 = lane & 15;
  const int ocl = wv * 16 + m16;

  f32x4 acc[13];
  int abase[13];
  #pragma unroll
  for (int mt = 0; mt < 13; ++mt) {
    acc[mt] = (f32x4)0.f;
    int p = mt * 16 + m16; if (p > 195) p = 195;
    int y = p / 14, x = p % 14;
    abase[mt] = (y * 16 + x) * 40 + q * 8;
  }

  for (int tap = 0; tap < 9; ++tap) {
    const int ky = tap / 3, kx = tap % 3;
    const int toff = (ky * 16 + kx) * 40;
    bf16x8 bfrag = *(const bf16x8*)&sW[tap * 2048 + ocl * 32 + q * 8];
    #pragma unroll
    for (int mt = 0; mt < 13; ++mt) {
      bf16x8 afrag = *(const bf16x8*)&sIn[abase[mt] + toff];
      acc[mt] = __builtin_amdgcn_mfma_f32_16x16x32_bf16(afrag, bfrag, acc[mt], 0, 0, 0);
    }
  }

  const float bias = sB[ocl];
  #pragma unroll
  for (int mt = 0; mt < 13; ++mt) {
    #pragma unroll
    for (int r = 0; r < 4; ++r) {
      int p = mt * 16 + q * 4 + r;
      if (p < 196) {
        float v = elu_f(acc[mt][r] + bias);
        short s = f2b(v);
        __builtin_memcpy(&d1o[(size_t)n * 12544 + p * 64 + ocl], &s, 2);
      }
    }
  }
}

// ---------------------------------------------------------------------------
// fused decoder conv2+conv3, BOTH on MFMA (parity decomposition).
// ---------------------------------------------------------------------------
__global__ __launch_bounds__(256) void k_d23(
    const unsigned* __restrict__ d1u,
    const int* __restrict__ idxbuf,
    const unsigned* __restrict__ wcb,
    const float* __restrict__ b2,
    const float* __restrict__ w3, const float* __restrict__ b3,
    float* __restrict__ out)
{
  __shared__ __align__(16) short sD1[256 * 72];
  __shared__ __align__(16) short sU[8192];
  __shared__ __align__(16) short sW3b[512];
  __shared__ float sC[196 * 9];
  __shared__ float sB2[32];

  const int n = blockIdx.x, t = threadIdx.x;
  const int e = idxbuf[n];

  {
    unsigned* d = (unsigned*)sD1;
    for (int idx = t; idx < 9216; idx += 256) d[idx] = 0u;
  }
  __syncthreads();
  {
    unsigned* d = (unsigned*)sD1;
    for (int idx = t; idx < 6272; idx += 256) {
      unsigned v = d1u[(size_t)n * 6272 + idx];
      int p = idx >> 5, icp = idx & 31;
      int r = p / 14, c = p % 14;
      d[((r + 1) * 16 + (c + 1)) * 36 + icp] = v;
    }
  }
  for (int j = t; j < 512; j += 256) {
    int nn = j >> 5, k = j & 31;
    sW3b[nn * 32 + k] = (nn < 9) ? f2b(w3[e * 288 + k * 9 + nn]) : (short)0;
  }
  if (t < 32) sB2[t] = b2[e * 32 + t];
  __syncthreads();

  const int wv = t >> 6, lane = t & 63;
  const int q = lane >> 4, m16 = lane & 15;
  const int nt = wv & 1, mh = wv >> 1;
  const int ocl = nt * 16 + m16;
  const int nm = (mh == 0) ? 7 : 6;

  const bf16x8 b3f = *(const bf16x8*)&sW3b[m16 * 32 + q * 8];

  int mt3[4], ab3[4];
  const int nmt3 = (wv == 0) ? 4 : 3;
  #pragma unroll
  for (int i = 0; i < 4; ++i) {
    int mt = wv + 4 * i; if (mt > 12) mt = 12;
    mt3[i] = mt;
    int p = mt * 16 + m16; if (p > 195) p = 195;
    ab3[i] = p * 40 + q * 8;
  }

  int PY[4], PX[4];
  #pragma unroll
  for (int g = 0; g < 4; ++g) {
    int P = t + 256 * g;
    PY[g] = (P < 784) ? P / 28 : -100;
    PX[g] = (P < 784) ? P % 28 : 0;
  }
  float racc[4] = {0.f, 0.f, 0.f, 0.f};

  int ab0[7];
  #pragma unroll
  for (int im = 0; im < 7; ++im) {
    int mt = mh + 2 * im;
    int p = mt * 16 + m16; if (p > 195) p = 195;
    int a = p / 14, bb = p % 14;
    ab0[im] = (a * 16 + bb) * 72 + q * 8;
  }

  for (int par = 0; par < 4; ++par) {
    const int py = par >> 1, px = par & 1;

    {
      const unsigned* wc = wcb + ((size_t)e * 4 + par) * 4096;
      unsigned* du = (unsigned*)sU;
      for (int v = t; v < 4096; v += 256) du[v] = wc[v];
    }
    __syncthreads();

    f32x4 acc[7];
    #pragma unroll
    for (int im = 0; im < 7; ++im) acc[im] = (f32x4)0.f;
    const int pbase = (py * 16 + px) * 72;
    for (int s = 0; s < 8; ++s) {
      int tap = s >> 1, h = s & 1;
      int ty = tap >> 1, tx = tap & 1;
      int toff = pbase + (ty * 16 + tx) * 72 + h * 32;
      bf16x8 bfrag = *(const bf16x8*)&sU[s * 1024 + ocl * 32 + q * 8];
      #pragma unroll
      for (int im = 0; im < 7; ++im) {
        if (im < nm) {
          bf16x8 afrag = *(const bf16x8*)&sD1[ab0[im] + toff];
          acc[im] = __builtin_amdgcn_mfma_f32_16x16x32_bf16(afrag, bfrag, acc[im], 0, 0, 0);
        }
      }
    }
    __syncthreads();

    {
      const float bias = sB2[ocl];
      #pragma unroll
      for (int im = 0; im < 7; ++im) {
        if (im < nm) {
          int mt = mh + 2 * im;
          #pragma unroll
          for (int r = 0; r < 4; ++r) {
            int p = mt * 16 + q * 4 + r;
            if (p < 196) sU[p * 40 + ocl] = f2b(elu_f(acc[im][r] + bias));
          }
        }
      }
    }
    __syncthreads();

    #pragma unroll
    for (int i = 0; i < 4; ++i) {
      if (i < nmt3) {
        bf16x8 af = *(const bf16x8*)&sU[ab3[i]];
        f32x4 a3 = (f32x4)0.f;
        a3 = __builtin_amdgcn_mfma_f32_16x16x32_bf16(af, b3f, a3, 0, 0, 0);
        if (m16 < 9) {
          #pragma unroll
          for (int r = 0; r < 4; ++r) {
            int p = mt3[i] * 16 + q * 4 + r;
            if (p < 196) sC[p * 9 + m16] = a3[r];
          }
        }
      }
    }
    __syncthreads();

    #pragma unroll
    for (int g = 0; g < 4; ++g) {
      const int Y = PY[g], X = PX[g];
      if (Y < 0) continue;
      int RS[2]; int nr = 0;
      if ((Y & 1) == py) { RS[0] = Y; nr = 1; }
      else { if (Y > 0) RS[nr++] = Y - 1; if (Y < 27) RS[nr++] = Y + 1; }
      int CS[2]; int nc = 0;
      if ((X & 1) == px) { CS[0] = X; nc = 1; }
      else { if (X > 0) CS[nc++] = X - 1; if (X < 27) CS[nc++] = X + 1; }
      float s = 0.f;
      for (int ir = 0; ir < nr; ++ir) {
        const int R = RS[ir];
        const int a = (R - py) >> 1, ky = R - Y + 1;
        for (int jc = 0; jc < nc; ++jc) {
          const int C = CS[jc];
          const int bq = (C - px) >> 1, kx = C - X + 1;
          s += sC[(a * 14 + bq) * 9 + ky * 3 + kx];
        }
      }
      racc[g] += s;
    }
    __syncthreads();
  }

  const float b3e = b3[e];
  #pragma unroll
  for (int g = 0; g < 4; ++g) {
    int P = t + 256 * g;
    if (P < 784)
      out[OFF_RECON + (size_t)n * 784 + P] = 1.f / (1.f + expf(-(racc[g] + b3e)));
  }
}

// ---------------------------------------------------------------------------
extern "C" void kernel_launch(void* const* d_in, const int* in_sizes, int n_in,
                              void* d_out, int out_size, void* d_ws, size_t ws_size,
                              hipStream_t stream) {
  const float* x    = (const float*)d_in[0];
  const float* eps  = (const float*)d_in[1];
  const float* ew1  = (const float*)d_in[2];
  const float* eb1  = (const float*)d_in[3];
  const float* ew2  = (const float*)d_in[4];
  const float* eb2  = (const float*)d_in[5];
  const float* ew3  = (const float*)d_in[6];
  const float* eb3  = (const float*)d_in[7];
  const float* wmu  = (const float*)d_in[8];
  const float* bmu  = (const float*)d_in[9];
  const float* wlv  = (const float*)d_in[10];
  const float* blv  = (const float*)d_in[11];
  const float* gw1  = (const float*)d_in[12];
  const float* gb1  = (const float*)d_in[13];
  const float* gw2  = (const float*)d_in[14];
  const float* gb2  = (const float*)d_in[15];
  const float* gw3  = (const float*)d_in[16];
  const float* gb3  = (const float*)d_in[17];
  const float* dfcw = (const float*)d_in[18];
  const float* dfcb = (const float*)d_in[19];
  const float* dw1  = (const float*)d_in[20];
  const float* db1  = (const float*)d_in[21];
  const float* dw2  = (const float*)d_in[22];
  const float* db2  = (const float*)d_in[23];
  const float* dw3  = (const float*)d_in[24];
  const float* db3  = (const float*)d_in[25];

  float* out = (float*)d_out;
  float* ws  = (float*)d_ws;

  float* U    = ws + WS_U;
  float* part = ws + WS_PART;
  float* zb   = ws + WS_Z;
  int*   idx  = (int*)(ws + WS_IDX);
  unsigned* hfcb = (unsigned*)(U + HFC_OFF);
  __hip_bfloat16* d1o = (__hip_bfloat16*)(U + D1O_OFF);
  unsigned short* w1b = (unsigned short*)(part + W1B_OFF);
  unsigned short* wcb = (unsigned short*)(part + WCB_OFF);
  unsigned short* w2s = (unsigned short*)(ws + WS_WENC + W2S_OFF);
  unsigned short* w3s = (unsigned short*)(ws + WS_WENC + W3S_OFF);

  k_prep_enc<<<1080, 256, 0, stream>>>(ew2, ew3, w2s, w3s);
  k_conv12<<<NB, 256, 0, stream>>>(x, ew1, eb1, eb2, w2s, U);
  k_conv3 <<<NB, 256, 0, stream>>>(U, w3s, eb3);
  k_fc    <<<dim3(32, 2, 2), 256, 0, stream>>>(U, wmu, wlv, part);
  k_gate  <<<32, 64, 0, stream>>>(part, bmu, blv, eps, gw1, gb1, gw2, gb2, gw3, gb3,
                                  out, zb, idx);
  k_prep  <<<dim3(8, 5), 256, 0, stream>>>(dw1, dw2, w1b, wcb);
  k_dfc   <<<NB, 256, 0, stream>>>(zb, idx, dfcw, dfcb, hfcb);
  k_d1    <<<NB, 256, 0, stream>>>(hfcb, idx, (const unsigned*)w1b, db1, d1o);
  k_d23   <<<NB, 256, 0, stream>>>((const unsigned*)d1o, idx, (const unsigned*)wcb,
                                   db2, dw3, db3, out);
}